// Round 1
// baseline (976.304 us; speedup 1.0000x reference)
//
#include <hip/hip_runtime.h>

#define ATT   1024
#define GM1   14     // G-1 groups actually written
#define LP1   16     // rows per class
#define GSIZE 64
#define NCLS  6000

// ---------------- table build ----------------
__global__ void init_tables(float* __restrict__ val_tab, int* __restrict__ msk_tab) {
    int i = blockIdx.x * blockDim.x + threadIdx.x;
    if (i < LP1 * ATT) { val_tab[i] = 0.f; msk_tab[i] = 0; }
}

__global__ void scatter_tables(const float* __restrict__ betas,
                               const int* __restrict__ gcols,
                               float* __restrict__ val_tab, int* __restrict__ msk_tab) {
    int t = blockIdx.x * blockDim.x + threadIdx.x;
    if (t >= GM1 * GSIZE) return;
    int k   = t >> 6;            // group 0..13  -> row k+2
    int col = gcols[t];
    int idx = ((k + 2) << 10) + col;
    msk_tab[idx] = 1;            // duplicate cols in a group write same value: benign
    val_tab[idx] = betas[k];
}

// ---------------- per-(class,row) inverse norms ----------------
__global__ __launch_bounds__(256) void norm_kernel(const float* __restrict__ attr,
                                                   const float* __restrict__ val_tab,
                                                   const int* __restrict__ msk_tab,
                                                   float* __restrict__ inv_norm) {
    int c = blockIdx.x;
    int t = threadIdx.x;
    const float* a = attr + (size_t)c * ATT;

    float acc[15];               // [0]=ssq, [1..14]=corrections for rows 2..15
#pragma unroll
    for (int k = 0; k < 15; ++k) acc[k] = 0.f;

#pragma unroll
    for (int it = 0; it < 4; ++it) {
        int ci = t + it * 256;
        float av = a[ci];
        float a2 = av * av;
        acc[0] += a2;
#pragma unroll
        for (int k = 0; k < GM1; ++k) {
            int idx = ((k + 2) << 10) + ci;
            if (msk_tab[idx]) {
                float v = val_tab[idx];
                acc[k + 1] += v * v - a2;
            }
        }
    }
    // wave(64)-level reduce, then cross-wave via LDS
#pragma unroll
    for (int k = 0; k < 15; ++k)
        for (int off = 32; off > 0; off >>= 1)
            acc[k] += __shfl_down(acc[k], off, 64);

    __shared__ float red[4][15];
    __shared__ float fin[16];
    int wave = t >> 6, lane = t & 63;
    if (lane == 0) {
#pragma unroll
        for (int k = 0; k < 15; ++k) red[wave][k] = acc[k];
    }
    __syncthreads();
    if (t < 15) fin[t] = red[0][t] + red[1][t] + red[2][t] + red[3][t];
    __syncthreads();
    if (t < 16) {
        float s   = (t < 2) ? fin[0] : fin[0] + fin[t - 1];
        float nrm = fmaxf(sqrtf(fmaxf(s, 0.f)), 1e-12f);
        inv_norm[c * 16 + t] = 1.0f / nrm;
    }
}

// ---------------- transposed-gather writer ----------------
// out[a, j] = m_norm[cls[j>>4], j&15, a];  one float4 = 4 consecutive j (same class)
__global__ __launch_bounds__(256) void writer(const float* __restrict__ attr,
                                              const float* __restrict__ val_tab,
                                              const int* __restrict__ msk_tab,
                                              const float* __restrict__ inv_norm,
                                              const int* __restrict__ cls,
                                              int n_pos, float* __restrict__ out) {
    int a_idx = blockIdx.y;                       // attribute column, fixed per block
    __shared__ float sval[16];
    __shared__ int   smsk[16];
    if (threadIdx.x < 16) {
        int idx = (threadIdx.x << 10) + a_idx;
        smsk[threadIdx.x] = msk_tab[idx];
        sval[threadIdx.x] = val_tab[idx];
    }
    __syncthreads();

    int W4 = n_pos * 4;                           // (n_pos*16)/4 float4s per row
    int j4 = blockIdx.x * blockDim.x + threadIdx.x;
    if (j4 >= W4) return;
    int j   = j4 << 2;
    int pos = j >> 4;
    int r0  = j & 15;                             // 0,4,8,12
    int c   = cls ? cls[pos] : pos;

    float  av  = attr[(size_t)c * ATT + a_idx];
    float4 inv = *(const float4*)(inv_norm + c * 16 + r0);

    float4 res;
    res.x = (smsk[r0 + 0] ? sval[r0 + 0] : av) * inv.x;
    res.y = (smsk[r0 + 1] ? sval[r0 + 1] : av) * inv.y;
    res.z = (smsk[r0 + 2] ? sval[r0 + 2] : av) * inv.z;
    res.w = (smsk[r0 + 3] ? sval[r0 + 3] : av) * inv.w;

    *(float4*)(out + (size_t)a_idx * ((size_t)n_pos * 16) + j) = res;
}

extern "C" void kernel_launch(void* const* d_in, const int* in_sizes, int n_in,
                              void* d_out, int out_size, void* d_ws, size_t ws_size,
                              hipStream_t stream) {
    const float* attr  = (const float*)d_in[0];
    const float* betas = (const float*)d_in[1];
    const int*   gcols = (const int*)d_in[2];
    const int*   uns   = (const int*)d_in[3];
    const int*   seen  = (const int*)d_in[4];
    float*       out   = (float*)d_out;

    char*  ws       = (char*)d_ws;
    float* val_tab  = (float*)ws;                  // 16*1024 f32 = 64 KB
    int*   msk_tab  = (int*)(ws + 65536);          // 16*1024 i32 = 64 KB
    float* inv_norm = (float*)(ws + 131072);       // 6000*16 f32 = 384 KB

    init_tables<<<64, 256, 0, stream>>>(val_tab, msk_tab);
    scatter_tables<<<4, 256, 0, stream>>>(betas, gcols, val_tab, msk_tab);
    norm_kernel<<<NCLS, 256, 0, stream>>>(attr, val_tab, msk_tab, inv_norm);

    const int N_UNSEEN = 1200, N_SEEN = 4800;
    {   // attribute_zsl: [1024, 19200]
        dim3 grid((N_UNSEEN * 4 + 255) / 256, ATT);
        writer<<<grid, 256, 0, stream>>>(attr, val_tab, msk_tab, inv_norm, uns, N_UNSEEN, out);
    }
    {   // attribute_seen: [1024, 76800]
        dim3 grid((N_SEEN * 4 + 255) / 256, ATT);
        writer<<<grid, 256, 0, stream>>>(attr, val_tab, msk_tab, inv_norm, seen, N_SEEN,
                                         out + (size_t)ATT * N_UNSEEN * 16);
    }
    {   // attribute_gzsl: [1024, 96000]
        dim3 grid((NCLS * 4 + 255) / 256, ATT);
        writer<<<grid, 256, 0, stream>>>(attr, val_tab, msk_tab, inv_norm, nullptr, NCLS,
                                         out + (size_t)ATT * (N_UNSEEN + N_SEEN) * 16);
    }
}